// Round 8
// baseline (190.296 us; speedup 1.0000x reference)
//
#include <hip/hip_runtime.h>

typedef unsigned short u16;
typedef __attribute__((ext_vector_type(8))) short short8;
typedef __attribute__((ext_vector_type(4))) float floatx4;

#define MFMA_BF16 __builtin_amdgcn_mfma_f32_16x16x32_bf16

__device__ __forceinline__ u16 f2bf(float f) {
    union { float f; unsigned int i; } v; v.f = f;
    unsigned int u = v.i;
    u += 0x7fffu + ((u >> 16) & 1u);   // round-to-nearest-even
    return (u16)(u >> 16);
}
__device__ __forceinline__ float leaky(float x) { return x >= 0.f ? x : 0.01f * x; }

#define H1S 264  // 256 + 8
#define RS 232   // 224 + 8
#define H3S 72   // 64 + 8
#define CS 136   // 128-col chunk stride (128 + 8)

// out-region offsets (elements)
#define O1 917504
#define O2 946176
#define O3 974848
#define O4 1003520

// packed-weight ws offsets (u16 elements)
#define PW1   0        // pm_w1  16*5*512  = 40960
#define PW3   40960    // pm_w3  32*8*512  = 131072
#define PWM2  172032   // pm_wm2 1*16*512  = 8192
#define PSW2  180224   // sm_w2  16*7*512  = 57344
#define PSW3  237568   // sm_w3  16*8*512  = 65536
#define PSW5  303104   // sm_w5  4*8*512   = 16384
#define PSW6  319488   // sm_w6  1*2*512   = 1024
#define PTOTAL 320512  // u16 elements -> 641024 bytes
#define WS_NEEDED 641024
#define WS_BIG (641024 + 3670016)   // + sp f32 [65536*14]

// ===========================================================================
// Merged pack kernel: all 7 weights f32 row-major -> bf16 fragment-major.
// ===========================================================================
struct PackSeg { const float* W; int K, N, S, base, count; };
struct PackArgs { PackSeg seg[7]; };

__global__ __launch_bounds__(256) void pack_all(PackArgs pa, u16* __restrict__ P) {
    int u = blockIdx.x * 256 + threadIdx.x;
    if (u >= PTOTAL) return;
#pragma unroll
    for (int i = 0; i < 7; i++) {
        if (u >= pa.seg[i].base && u < pa.seg[i].base + pa.seg[i].count) {
            int v = u - pa.seg[i].base;
            int j = v & 7;
            int l = (v >> 3) & 63;
            int ts = v >> 9;
            int s = ts % pa.seg[i].S;
            int t = ts / pa.seg[i].S;
            int k = s * 32 + (l >> 4) * 8 + j;
            int n = t * 16 + (l & 15);
            P[u] = (k < pa.seg[i].K && n < pa.seg[i].N)
                       ? f2bf(pa.seg[i].W[k * pa.seg[i].N + n]) : (u16)0;
            return;
        }
    }
}

// Build an L1 A-fragment for the PM path straight from global f32 X.
// cols = s*32 + q*8 .. +7, row length 140; cols >= 140 are zero.
__device__ __forceinline__ short8 load_x_frag(const float* __restrict__ X,
                                              int row, int s, int q) {
    const float* p = X + row * 140;
    float4 v0 = {0.f, 0.f, 0.f, 0.f}, v1 = {0.f, 0.f, 0.f, 0.f};
    int col0 = s * 32 + q * 8;
    if (s < 4) {                       // compile-time (s unrolled): cols <= 127+12 < 140
        v0 = *(const float4*)(p + col0);
        v1 = *(const float4*)(p + col0 + 4);
    } else {                           // s == 4: cols 128..159, valid < 140
        if (q <= 1) v0 = *(const float4*)(p + col0);       // q0:128-131(135) q1:136-139
        if (q == 0) v1 = *(const float4*)(p + col0 + 4);   // q0:132-135
    }
    short8 r;
    r[0] = (short)f2bf(v0.x); r[1] = (short)f2bf(v0.y);
    r[2] = (short)f2bf(v0.z); r[3] = (short)f2bf(v0.w);
    r[4] = (short)f2bf(v1.x); r[5] = (short)f2bf(v1.y);
    r[6] = (short)f2bf(v1.z); r[7] = (short)f2bf(v1.w);
    return r;
}

// ===========================================================================
// Merged MLP kernel:
//   blocks 0..63    : sensor model, 32 unique rows each -> ez (out+O4)
//   blocks 64..1087 : process model, 64 rows (2 batches) each -> sp_ws
// PM: L1 A-fragments direct from global (no X staging); L2 in 4x128-col
// chunks, each followed by an L3 partial (1 k-step/wave).
// LDS: 64*264*2 + 64*136*2 = 50.0 KB -> 3 blocks/CU.
// ===========================================================================
__global__ __launch_bounds__(256) void merged_mlp(
    const float* __restrict__ Rg, const float* __restrict__ Xg,
    const u16* __restrict__ Pk,
    const float* __restrict__ b1, const float* __restrict__ b3,
    const float* __restrict__ bm2,
    const float* __restrict__ b2, const float* __restrict__ sb3,
    const float* __restrict__ b5, const float* __restrict__ b6,
    float* __restrict__ ez_out,   // out + O4
    float* __restrict__ sp_ws)    // [65536*14]
{
    __shared__ __align__(16) u16 ldsH[64 * H1S];  // PM: h1 -> pacc ; SM: raw -> h2 -> pacc
    __shared__ __align__(16) u16 ldsC[64 * CS];   // PM: h2 chunk ; SM: h1 -> h3

    const int tid  = threadIdx.x;
    const int lane = tid & 63;
    const int wave = tid >> 6;
    const int q    = lane >> 4;
    const int n16  = lane & 15;

    if (blockIdx.x < 64) {
        // ---------------- sensor model path (32 rows) ----------------
        const u16* w2p = Pk + PSW2;
        const u16* w3p = Pk + PSW3;
        const u16* w5p = Pk + PSW5;
        const u16* w6p = Pk + PSW6;
        const int row0 = blockIdx.x * 32;

        for (int idx = tid; idx < 32 * 56; idx += 256) {
            int r = idx / 56, c4 = idx - r * 56;
            float4 v = {0.f, 0.f, 0.f, 0.f};
            if (c4 < 55) v = *(const float4*)&Rg[(row0 + r) * 220 + c4 * 4];
            u16* dst = &ldsH[r * RS + c4 * 4];
            dst[0] = f2bf(v.x); dst[1] = f2bf(v.y); dst[2] = f2bf(v.z); dst[3] = f2bf(v.w);
        }
        __syncthreads();

        // L1: 224K -> 256 (raw in ldsH -> h1 in ldsC)
        {
            floatx4 zero = {0.f, 0.f, 0.f, 0.f};
            floatx4 acc[2][4];
            for (int rt = 0; rt < 2; rt++)
                for (int ct = 0; ct < 4; ct++) acc[rt][ct] = zero;
#pragma unroll
            for (int s = 0; s < 7; s++) {
                short8 a0 = *(const short8*)&ldsH[n16 * RS + s * 32 + q * 8];
                short8 a1 = *(const short8*)&ldsH[(n16 + 16) * RS + s * 32 + q * 8];
#pragma unroll
                for (int ct = 0; ct < 4; ct++) {
                    int t = wave * 4 + ct;
                    short8 bf = *(const short8*)&w2p[((t * 7 + s) * 64 + lane) * 8];
                    acc[0][ct] = MFMA_BF16(a0, bf, acc[0][ct], 0, 0, 0);
                    acc[1][ct] = MFMA_BF16(a1, bf, acc[1][ct], 0, 0, 0);
                }
            }
#pragma unroll
            for (int ct = 0; ct < 4; ct++) {
                int col = (wave * 4 + ct) * 16 + n16;
                float bias = b2[col];
#pragma unroll
                for (int rt = 0; rt < 2; rt++)
#pragma unroll
                    for (int r = 0; r < 4; r++)
                        ldsC[(rt * 16 + q * 4 + r) * H1S + col] = f2bf(leaky(acc[rt][ct][r] + bias));
            }
        }
        __syncthreads();

        // L2: 256 -> 256 (h1 in ldsC -> h2 in ldsH; raw dead)
        {
            floatx4 zero = {0.f, 0.f, 0.f, 0.f};
            floatx4 acc[2][4];
            for (int rt = 0; rt < 2; rt++)
                for (int ct = 0; ct < 4; ct++) acc[rt][ct] = zero;
#pragma unroll
            for (int s = 0; s < 8; s++) {
                short8 a0 = *(const short8*)&ldsC[n16 * H1S + s * 32 + q * 8];
                short8 a1 = *(const short8*)&ldsC[(n16 + 16) * H1S + s * 32 + q * 8];
#pragma unroll
                for (int ct = 0; ct < 4; ct++) {
                    int t = wave * 4 + ct;
                    short8 bf = *(const short8*)&w3p[((t * 8 + s) * 64 + lane) * 8];
                    acc[0][ct] = MFMA_BF16(a0, bf, acc[0][ct], 0, 0, 0);
                    acc[1][ct] = MFMA_BF16(a1, bf, acc[1][ct], 0, 0, 0);
                }
            }
#pragma unroll
            for (int ct = 0; ct < 4; ct++) {
                int col = (wave * 4 + ct) * 16 + n16;
                float bias = sb3[col];
#pragma unroll
                for (int rt = 0; rt < 2; rt++)
#pragma unroll
                    for (int r = 0; r < 4; r++)
                        ldsH[(rt * 16 + q * 4 + r) * H1S + col] = f2bf(leaky(acc[rt][ct][r] + bias));
            }
        }
        __syncthreads();

        // L3: 256 -> 64 (h2 in ldsH -> h3 in ldsC; h1 dead)
        {
            floatx4 zero = {0.f, 0.f, 0.f, 0.f};
            floatx4 acc[2] = {zero, zero};
#pragma unroll
            for (int s = 0; s < 8; s++) {
                short8 a0 = *(const short8*)&ldsH[n16 * H1S + s * 32 + q * 8];
                short8 a1 = *(const short8*)&ldsH[(n16 + 16) * H1S + s * 32 + q * 8];
                short8 bf = *(const short8*)&w5p[((wave * 8 + s) * 64 + lane) * 8];
                acc[0] = MFMA_BF16(a0, bf, acc[0], 0, 0, 0);
                acc[1] = MFMA_BF16(a1, bf, acc[1], 0, 0, 0);
            }
            int col = wave * 16 + n16;
            float bias = b5[col];
#pragma unroll
            for (int rt = 0; rt < 2; rt++)
#pragma unroll
                for (int r = 0; r < 4; r++)
                    ldsC[(rt * 16 + q * 4 + r) * H3S + col] = f2bf(leaky(acc[rt][r] + bias));
        }
        __syncthreads();

        // L4: 64 -> 16(14), waves 0,1 split K; pacc in ldsH (h2 dead)
        if (wave < 2) {
            floatx4 zero = {0.f, 0.f, 0.f, 0.f};
            floatx4 acc[2] = {zero, zero};
            int s = wave;
            short8 a0 = *(const short8*)&ldsC[n16 * H3S + s * 32 + q * 8];
            short8 a1 = *(const short8*)&ldsC[(n16 + 16) * H3S + s * 32 + q * 8];
            short8 bf = *(const short8*)&w6p[(s * 64 + lane) * 8];
            acc[0] = MFMA_BF16(a0, bf, acc[0], 0, 0, 0);
            acc[1] = MFMA_BF16(a1, bf, acc[1], 0, 0, 0);
            float* pacc = (float*)ldsH;
#pragma unroll
            for (int rt = 0; rt < 2; rt++)
#pragma unroll
                for (int r = 0; r < 4; r++)
                    pacc[(wave * 32 + rt * 16 + q * 4 + r) * 16 + n16] = acc[rt][r];
        }
        __syncthreads();
        {
            const float* pacc = (const float*)ldsH;
            for (int idx = tid; idx < 512; idx += 256) {
                int r = idx >> 4, c = idx & 15;
                float v = pacc[idx] + pacc[512 + idx];
                if (c < 14) ez_out[(row0 + r) * 14 + c] = v + b6[c];
            }
        }
    } else {
        // ---------------- process model path (64 rows = 2 batches) ----------------
        const u16* w1p  = Pk + PW1;
        const u16* w3p  = Pk + PW3;
        const u16* wm2p = Pk + PWM2;
        const int bb   = blockIdx.x - 64;   // 0..1023
        const int row0 = bb * 64;

        // L1: [64x160] @ [160x256] -> h1 in ldsH ; A-fragments direct from global
        {
            floatx4 zero = {0.f, 0.f, 0.f, 0.f};
            floatx4 acc[4][4];
            for (int rt = 0; rt < 4; rt++)
                for (int ct = 0; ct < 4; ct++) acc[rt][ct] = zero;
#pragma unroll
            for (int s = 0; s < 5; s++) {
                short8 a[4];
#pragma unroll
                for (int rt = 0; rt < 4; rt++)
                    a[rt] = load_x_frag(Xg, row0 + rt * 16 + n16, s, q);
#pragma unroll
                for (int ct = 0; ct < 4; ct++) {
                    int t = wave * 4 + ct;
                    short8 bf = *(const short8*)&w1p[((t * 5 + s) * 64 + lane) * 8];
#pragma unroll
                    for (int rt = 0; rt < 4; rt++)
                        acc[rt][ct] = MFMA_BF16(a[rt], bf, acc[rt][ct], 0, 0, 0);
                }
            }
#pragma unroll
            for (int ct = 0; ct < 4; ct++) {
                int col = (wave * 4 + ct) * 16 + n16;
                float bias = b1[col];
#pragma unroll
                for (int rt = 0; rt < 4; rt++)
#pragma unroll
                    for (int r = 0; r < 4; r++)
                        ldsH[(rt * 16 + q * 4 + r) * H1S + col] = f2bf(leaky(acc[rt][ct][r] + bias));
            }
        }
        __syncthreads();   // h1 published

        // L2 in 4x128-col chunks + L3 partial accumulation per chunk
        floatx4 acc3[4];
        {
            floatx4 zero = {0.f, 0.f, 0.f, 0.f};
            for (int rt = 0; rt < 4; rt++) acc3[rt] = zero;
        }
#pragma unroll
        for (int c = 0; c < 4; c++) {
            // L2 chunk: h1 [64x256] @ w3[:, c*128:(c+1)*128] -> ldsC (stride CS)
            {
                floatx4 zero = {0.f, 0.f, 0.f, 0.f};
                floatx4 acc[4][2];
                for (int rt = 0; rt < 4; rt++)
                    for (int ct = 0; ct < 2; ct++) acc[rt][ct] = zero;
#pragma unroll
                for (int s = 0; s < 8; s++) {
                    short8 a[4];
#pragma unroll
                    for (int rt = 0; rt < 4; rt++)
                        a[rt] = *(const short8*)&ldsH[(rt * 16 + n16) * H1S + s * 32 + q * 8];
#pragma unroll
                    for (int ct = 0; ct < 2; ct++) {
                        int tg = c * 8 + wave * 2 + ct;
                        short8 bf = *(const short8*)&w3p[((tg * 8 + s) * 64 + lane) * 8];
#pragma unroll
                        for (int rt = 0; rt < 4; rt++)
                            acc[rt][ct] = MFMA_BF16(a[rt], bf, acc[rt][ct], 0, 0, 0);
                    }
                }
                // ldsC free: chunk 0 -> first PM use; chunk >0 -> barrier 2 below.
#pragma unroll
                for (int ct = 0; ct < 2; ct++) {
                    int cl = (wave * 2 + ct) * 16 + n16;      // 0..127 within chunk
                    float bias = b3[c * 128 + cl];
#pragma unroll
                    for (int rt = 0; rt < 4; rt++)
#pragma unroll
                        for (int r = 0; r < 4; r++)
                            ldsC[(rt * 16 + q * 4 + r) * CS + cl] = f2bf(leaky(acc[rt][ct][r] + bias));
                }
            }
            __syncthreads();   // barrier 1: h2 chunk published
            // L3 partial: this chunk's 4 k-steps, one per wave
            {
                int sg = c * 4 + wave;               // global k-step 0..15
                short8 bf = *(const short8*)&wm2p[(sg * 64 + lane) * 8];
#pragma unroll
                for (int rt = 0; rt < 4; rt++) {
                    short8 a = *(const short8*)&ldsC[(rt * 16 + n16) * CS + wave * 32 + q * 8];
                    acc3[rt] = MFMA_BF16(a, bf, acc3[rt], 0, 0, 0);
                }
            }
            __syncthreads();   // barrier 2: ldsC consumed, next chunk may overwrite
        }

        // reduce partial L3 sums across waves via pacc in ldsH (h1 dead)
        {
            float* pacc = (float*)ldsH;
#pragma unroll
            for (int rt = 0; rt < 4; rt++)
#pragma unroll
                for (int r = 0; r < 4; r++)
                    pacc[(wave * 64 + rt * 16 + q * 4 + r) * 16 + n16] = acc3[rt][r];
        }
        __syncthreads();
        {
            const float* pacc = (const float*)ldsH;
            for (int idx = tid; idx < 1024; idx += 256) {
                int r = idx >> 4, c = idx & 15;
                float v = pacc[idx] + pacc[1024 + idx] + pacc[2048 + idx] + pacc[3072 + idx];
                if (c < 14) sp_ws[(row0 + r) * 14 + c] = v + bm2[c];
            }
        }
    }
}

// ===========================================================================
// EnKF tail: one 64-thread wave per batch, no barriers (in-order LDS), tiny
// LDS -> many resident blocks/CU -> cross-batch latency overlap.
// Corrected mean computed analytically: mean(corr) = sm + K @ (zz - sm).
// ===========================================================================
__global__ __launch_bounds__(64) void enkf_tail(
    const float* __restrict__ sp_all,
    const float* __restrict__ on_w1, const float* __restrict__ on_b1,
    const float* __restrict__ on_w2, const float* __restrict__ on_b2,
    float* out)
{
    __shared__ float spv[32][14];
    __shared__ float ezv[32][14];
    __shared__ float smv[14], zzv[14], rrv[14];
    __shared__ float M[14][14], Kmat[14][14];
    __shared__ float G[14][28];
    __shared__ float fac[14];
    __shared__ float hbuf[32];

    const int l = threadIdx.x;
    const int b = blockIdx.x;

    for (int idx = l; idx < 448; idx += 64) ((float*)spv)[idx] = sp_all[b * 448 + idx];
    {
        const float* ezsrc = out + O4 + (b & 63) * 448;
        for (int idx = l; idx < 448; idx += 64) ((float*)ezv)[idx] = ezsrc[idx];
    }

    if (l < 14) {
        float s1 = 0.f, s2 = 0.f;
        for (int e = 0; e < 32; e++) { s1 += spv[e][l]; s2 += ezv[e][l]; }
        smv[l] = s1 * (1.f / 32.f);
        zzv[l] = s2 * (1.f / 32.f);
    }
    if (l < 32) {
        float t = on_b1[l];
        for (int k = 0; k < 14; k++) t += zzv[k] * on_w1[k * 32 + l];
        hbuf[l] = t > 0.f ? t : 0.f;
    }
    if (l < 14) {
        float t = on_b2[l];
        for (int k = 0; k < 32; k++) t += hbuf[k] * on_w2[k * 14 + l];
        t += 0.001f;
        rrv[l] = t * t + 0.038729833f;
    }
    for (int idx = l; idx < 196; idx += 64) {
        int i = idx / 14, j = idx - i * 14;
        float s = 0.f;
        for (int e = 0; e < 32; e++) s += (spv[e][i] - smv[i]) * (spv[e][j] - smv[j]);
        s *= (1.f / 31.f);
        M[i][j] = s;
        G[i][j] = s + (i == j ? rrv[i] : 0.f);
        G[i][14 + j] = (i == j) ? 1.f : 0.f;
    }
    // Gauss-Jordan (SPD, no pivoting), single-wave in-order
    for (int c = 0; c < 14; c++) {
        float pinv = 1.f / G[c][c];
        if (l < 28) G[c][l] *= pinv;
        if (l < 14 && l != c) fac[l] = G[l][c];
        for (int idx = l; idx < 392; idx += 64) {
            int i = idx / 28, j = idx - i * 28;
            if (i != c) G[i][j] -= fac[i] * G[c][j];
        }
    }
    for (int idx = l; idx < 196; idx += 64) {
        int i = idx / 14, j = idx - i * 14;
        float s = 0.f;
        for (int k = 0; k < 14; k++) s += M[i][k] * G[k][14 + j];
        Kmat[i][j] = s;
    }
    for (int idx = l; idx < 448; idx += 64) {
        int e = idx / 14, i = idx - e * 14;
        float g = 0.f;
        for (int j = 0; j < 14; j++) g += Kmat[i][j] * (ezv[e][j] - spv[e][j]);
        out[b * 448 + idx] = spv[e][i] + g;      // state_corrected
        out[O4 + b * 448 + idx] = ezv[e][i];     // ensemble_z
    }
    if (l < 14) {
        float g = 0.f;
        for (int j = 0; j < 14; j++) g += Kmat[l][j] * (zzv[j] - smv[j]);
        out[O1 + b * 14 + l] = smv[l] + g;       // corrected mean (linearity)
        out[O2 + b * 14 + l] = smv[l];           // state_m
        out[O3 + b * 14 + l] = zzv[l];           // z
    }
}

// ===========================================================================
extern "C" void kernel_launch(void* const* d_in, const int* in_sizes, int n_in,
                              void* d_out, int out_size, void* d_ws, size_t ws_size,
                              hipStream_t stream) {
    (void)in_sizes; (void)n_in; (void)out_size; (void)ws_size;
    // ws_size >= WS_BIG verified empirically in R6/R7 (merged path ran & passed).

    const float* raw_obs    = (const float*)d_in[0];
    const float* state_prev = (const float*)d_in[1];
    const float* pm_w1  = (const float*)d_in[2];
    const float* pm_b1  = (const float*)d_in[3];
    const float* pm_w3  = (const float*)d_in[4];
    const float* pm_b3  = (const float*)d_in[5];
    const float* pm_wm2 = (const float*)d_in[6];
    const float* pm_bm2 = (const float*)d_in[7];
    const float* sm_w2  = (const float*)d_in[8];
    const float* sm_b2  = (const float*)d_in[9];
    const float* sm_w3  = (const float*)d_in[10];
    const float* sm_b3  = (const float*)d_in[11];
    const float* sm_w5  = (const float*)d_in[12];
    const float* sm_b5  = (const float*)d_in[13];
    const float* sm_w6  = (const float*)d_in[14];
    const float* sm_b6  = (const float*)d_in[15];
    const float* on_w1  = (const float*)d_in[16];
    const float* on_b1  = (const float*)d_in[17];
    const float* on_w2  = (const float*)d_in[18];
    const float* on_b2  = (const float*)d_in[19];

    float* out = (float*)d_out;
    u16* P = (u16*)d_ws;
    float* sp_ws = (float*)((char*)d_ws + WS_NEEDED);

    PackArgs pa;
    pa.seg[0] = { pm_w1,  140, 256, 5,  PW1,  40960  };
    pa.seg[1] = { pm_w3,  256, 512, 8,  PW3,  131072 };
    pa.seg[2] = { pm_wm2, 512, 14,  16, PWM2, 8192   };
    pa.seg[3] = { sm_w2,  220, 256, 7,  PSW2, 57344  };
    pa.seg[4] = { sm_w3,  256, 256, 8,  PSW3, 65536  };
    pa.seg[5] = { sm_w5,  256, 64,  8,  PSW5, 16384  };
    pa.seg[6] = { sm_w6,  64,  14,  2,  PSW6, 1024   };
    pack_all<<<(PTOTAL + 255) / 256, 256, 0, stream>>>(pa, P);

    merged_mlp<<<1088, 256, 0, stream>>>(raw_obs, state_prev, P,
                                         pm_b1, pm_b3, pm_bm2,
                                         sm_b2, sm_b3, sm_b5, sm_b6,
                                         out + O4, sp_ws);
    enkf_tail<<<2048, 64, 0, stream>>>(sp_ws, on_w1, on_b1, on_w2, on_b2, out);
}

// Round 9
// 181.977 us; speedup vs baseline: 1.0457x; 1.0457x over previous
//
#include <hip/hip_runtime.h>

typedef unsigned short u16;
typedef __attribute__((ext_vector_type(8))) short short8;
typedef __attribute__((ext_vector_type(4))) float floatx4;

#define MFMA_BF16 __builtin_amdgcn_mfma_f32_16x16x32_bf16

__device__ __forceinline__ u16 f2bf(float f) {
    union { float f; unsigned int i; } v; v.f = f;
    unsigned int u = v.i;
    u += 0x7fffu + ((u >> 16) & 1u);   // round-to-nearest-even
    return (u16)(u >> 16);
}
__device__ __forceinline__ float leaky(float x) { return x >= 0.f ? x : 0.01f * x; }

#define H1S 264  // 256 + 8
#define RS 232   // 224 + 8
#define H3S 72   // 64 + 8
#define CS 136   // 128-col chunk stride (128 + 8)

// out-region offsets (elements)
#define O1 917504
#define O2 946176
#define O3 974848
#define O4 1003520

// packed-weight ws offsets (u16 elements)
#define PW1   0        // pm_w1  16*5*512  = 40960
#define PW3   40960    // pm_w3  32*8*512  = 131072
#define PWM2  172032   // pm_wm2 1*16*512  = 8192
#define PSW2  180224   // sm_w2  16*7*512  = 57344
#define PSW3  237568   // sm_w3  16*8*512  = 65536
#define PSW5  303104   // sm_w5  4*8*512   = 16384
#define PSW6  319488   // sm_w6  1*2*512   = 1024
#define PTOTAL 320512  // u16 elements -> 641024 bytes
#define WS_NEEDED 641024
#define WS_BIG (641024 + 3670016)   // + sp f32 [65536*14]

// ===========================================================================
// Merged pack kernel: all 7 weights f32 row-major -> bf16 fragment-major.
// ===========================================================================
struct PackSeg { const float* W; int K, N, S, base, count; };
struct PackArgs { PackSeg seg[7]; };

__global__ __launch_bounds__(256) void pack_all(PackArgs pa, u16* __restrict__ P) {
    int u = blockIdx.x * 256 + threadIdx.x;
    if (u >= PTOTAL) return;
#pragma unroll
    for (int i = 0; i < 7; i++) {
        if (u >= pa.seg[i].base && u < pa.seg[i].base + pa.seg[i].count) {
            int v = u - pa.seg[i].base;
            int j = v & 7;
            int l = (v >> 3) & 63;
            int ts = v >> 9;
            int s = ts % pa.seg[i].S;
            int t = ts / pa.seg[i].S;
            int k = s * 32 + (l >> 4) * 8 + j;
            int n = t * 16 + (l & 15);
            P[u] = (k < pa.seg[i].K && n < pa.seg[i].N)
                       ? f2bf(pa.seg[i].W[k * pa.seg[i].N + n]) : (u16)0;
            return;
        }
    }
}

// Build an L1 A-fragment for the PM path straight from global f32 X.
// cols = s*32 + q*8 .. +7, row length 140; cols >= 140 are zero.
__device__ __forceinline__ short8 load_x_frag(const float* __restrict__ X,
                                              int row, int s, int q) {
    const float* p = X + row * 140;
    float4 v0 = {0.f, 0.f, 0.f, 0.f}, v1 = {0.f, 0.f, 0.f, 0.f};
    int col0 = s * 32 + q * 8;
    if (s < 4) {
        v0 = *(const float4*)(p + col0);
        v1 = *(const float4*)(p + col0 + 4);
    } else {
        if (q <= 1) v0 = *(const float4*)(p + col0);
        if (q == 0) v1 = *(const float4*)(p + col0 + 4);
    }
    short8 r;
    r[0] = (short)f2bf(v0.x); r[1] = (short)f2bf(v0.y);
    r[2] = (short)f2bf(v0.z); r[3] = (short)f2bf(v0.w);
    r[4] = (short)f2bf(v1.x); r[5] = (short)f2bf(v1.y);
    r[6] = (short)f2bf(v1.z); r[7] = (short)f2bf(v1.w);
    return r;
}

// ===========================================================================
// Merged MLP kernel, 32 rows/block everywhere:
//   blocks 0..63    : sensor model (2048 unique rows) -> ez (out+O4)
//   blocks 64..2111 : process model, 1 batch each -> sp_ws
// LDS = ldsH 16.9 KB + ldsC 8.7 KB = 25.6 KB -> 6 blocks/CU by LDS;
// __launch_bounds__(256,5) caps VGPR ~102 -> ~5 blocks/CU resident.
// Grid depth 8.25 blocks/CU sustains the occupancy (R8's 64-row grid could not).
// ===========================================================================
__global__ __launch_bounds__(256, 5) void merged_mlp(
    const float* __restrict__ Rg, const float* __restrict__ Xg,
    const u16* __restrict__ Pk,
    const float* __restrict__ b1, const float* __restrict__ b3,
    const float* __restrict__ bm2,
    const float* __restrict__ b2, const float* __restrict__ sb3,
    const float* __restrict__ b5, const float* __restrict__ b6,
    float* __restrict__ ez_out,   // out + O4
    float* __restrict__ sp_ws)    // [65536*14]
{
    __shared__ __align__(16) u16 ldsH[32 * H1S];  // raw/h1/pacc
    __shared__ __align__(16) u16 ldsC[32 * CS];   // h2 chunks / h3

    const int tid  = threadIdx.x;
    const int lane = tid & 63;
    const int wave = tid >> 6;
    const int q    = lane >> 4;
    const int n16  = lane & 15;

    if (blockIdx.x < 64) {
        // ---------------- sensor model path (32 rows) ----------------
        const u16* w2p = Pk + PSW2;
        const u16* w3p = Pk + PSW3;
        const u16* w5p = Pk + PSW5;
        const u16* w6p = Pk + PSW6;
        const int row0 = blockIdx.x * 32;

        // stage raw (f32 -> bf16), zero-pad 220 -> 224, into ldsH (stride RS)
        for (int idx = tid; idx < 32 * 56; idx += 256) {
            int r = idx / 56, c4 = idx - r * 56;
            float4 v = {0.f, 0.f, 0.f, 0.f};
            if (c4 < 55) v = *(const float4*)&Rg[(row0 + r) * 220 + c4 * 4];
            u16* dst = &ldsH[r * RS + c4 * 4];
            dst[0] = f2bf(v.x); dst[1] = f2bf(v.y); dst[2] = f2bf(v.z); dst[3] = f2bf(v.w);
        }
        __syncthreads();

        // L1: 224K -> 256 ; results held in regs, then h1 overwrites raw in ldsH
        floatx4 acc1[2][4];
        {
            floatx4 zero = {0.f, 0.f, 0.f, 0.f};
            for (int rt = 0; rt < 2; rt++)
                for (int ct = 0; ct < 4; ct++) acc1[rt][ct] = zero;
#pragma unroll
            for (int s = 0; s < 7; s++) {
                short8 a0 = *(const short8*)&ldsH[n16 * RS + s * 32 + q * 8];
                short8 a1 = *(const short8*)&ldsH[(n16 + 16) * RS + s * 32 + q * 8];
#pragma unroll
                for (int ct = 0; ct < 4; ct++) {
                    int t = wave * 4 + ct;
                    short8 bf = *(const short8*)&w2p[((t * 7 + s) * 64 + lane) * 8];
                    acc1[0][ct] = MFMA_BF16(a0, bf, acc1[0][ct], 0, 0, 0);
                    acc1[1][ct] = MFMA_BF16(a1, bf, acc1[1][ct], 0, 0, 0);
                }
            }
        }
        __syncthreads();   // all raw reads done
#pragma unroll
        for (int ct = 0; ct < 4; ct++) {
            int col = (wave * 4 + ct) * 16 + n16;
            float bias = b2[col];
#pragma unroll
            for (int rt = 0; rt < 2; rt++)
#pragma unroll
                for (int r = 0; r < 4; r++)
                    ldsH[(rt * 16 + q * 4 + r) * H1S + col] = f2bf(leaky(acc1[rt][ct][r] + bias));
        }
        __syncthreads();   // h1 published

        // L2 (2 chunks of 128 cols) + interleaved L3 partials (256 -> 64)
        floatx4 acc5[2];
        {
            floatx4 zero = {0.f, 0.f, 0.f, 0.f};
            acc5[0] = zero; acc5[1] = zero;
        }
#pragma unroll
        for (int c = 0; c < 2; c++) {
            floatx4 zero = {0.f, 0.f, 0.f, 0.f};
            floatx4 acc[2][2];
            for (int rt = 0; rt < 2; rt++)
                for (int ct = 0; ct < 2; ct++) acc[rt][ct] = zero;
#pragma unroll
            for (int s = 0; s < 8; s++) {
                short8 a0 = *(const short8*)&ldsH[n16 * H1S + s * 32 + q * 8];
                short8 a1 = *(const short8*)&ldsH[(n16 + 16) * H1S + s * 32 + q * 8];
#pragma unroll
                for (int ct = 0; ct < 2; ct++) {
                    int tg = c * 8 + wave * 2 + ct;
                    short8 bf = *(const short8*)&w3p[((tg * 8 + s) * 64 + lane) * 8];
                    acc[0][ct] = MFMA_BF16(a0, bf, acc[0][ct], 0, 0, 0);
                    acc[1][ct] = MFMA_BF16(a1, bf, acc[1][ct], 0, 0, 0);
                }
            }
#pragma unroll
            for (int ct = 0; ct < 2; ct++) {
                int cl = (wave * 2 + ct) * 16 + n16;
                float bias = sb3[c * 128 + cl];
#pragma unroll
                for (int rt = 0; rt < 2; rt++)
#pragma unroll
                    for (int r = 0; r < 4; r++)
                        ldsC[(rt * 16 + q * 4 + r) * CS + cl] = f2bf(leaky(acc[rt][ct][r] + bias));
            }
            __syncthreads();   // h2 chunk published
            // L3 partial: wave owns output col-tile `wave`; 4 k-steps in chunk
#pragma unroll
            for (int sl = 0; sl < 4; sl++) {
                int sg = c * 4 + sl;   // global k-step 0..7
                short8 bf = *(const short8*)&w5p[((wave * 8 + sg) * 64 + lane) * 8];
#pragma unroll
                for (int rt = 0; rt < 2; rt++) {
                    short8 a = *(const short8*)&ldsC[(rt * 16 + n16) * CS + sl * 32 + q * 8];
                    acc5[rt] = MFMA_BF16(a, bf, acc5[rt], 0, 0, 0);
                }
            }
            __syncthreads();   // chunk consumed
        }

        // h3 -> ldsC (stride H3S)
        {
            int col = wave * 16 + n16;
            float bias = b5[col];
#pragma unroll
            for (int rt = 0; rt < 2; rt++)
#pragma unroll
                for (int r = 0; r < 4; r++)
                    ldsC[(rt * 16 + q * 4 + r) * H3S + col] = f2bf(leaky(acc5[rt][r] + bias));
        }
        __syncthreads();

        // L4: 64 -> 16(14), waves 0,1 split K; pacc in ldsH (h1 dead)
        if (wave < 2) {
            floatx4 zero = {0.f, 0.f, 0.f, 0.f};
            floatx4 acc[2] = {zero, zero};
            int s = wave;
            short8 a0 = *(const short8*)&ldsC[n16 * H3S + s * 32 + q * 8];
            short8 a1 = *(const short8*)&ldsC[(n16 + 16) * H3S + s * 32 + q * 8];
            short8 bf = *(const short8*)&w6p[(s * 64 + lane) * 8];
            acc[0] = MFMA_BF16(a0, bf, acc[0], 0, 0, 0);
            acc[1] = MFMA_BF16(a1, bf, acc[1], 0, 0, 0);
            float* pacc = (float*)ldsH;
#pragma unroll
            for (int rt = 0; rt < 2; rt++)
#pragma unroll
                for (int r = 0; r < 4; r++)
                    pacc[(wave * 32 + rt * 16 + q * 4 + r) * 16 + n16] = acc[rt][r];
        }
        __syncthreads();
        {
            const float* pacc = (const float*)ldsH;
            for (int idx = tid; idx < 512; idx += 256) {
                int r = idx >> 4, c = idx & 15;
                float v = pacc[idx] + pacc[512 + idx];
                if (c < 14) ez_out[(row0 + r) * 14 + c] = v + b6[c];
            }
        }
    } else {
        // ---------------- process model path (32 rows = 1 batch) ----------------
        const u16* w1p  = Pk + PW1;
        const u16* w3p  = Pk + PW3;
        const u16* wm2p = Pk + PWM2;
        const int bb   = blockIdx.x - 64;   // 0..2047
        const int row0 = bb * 32;

        // L1: [32x160] @ [160x256] -> h1 in ldsH ; A-fragments direct from global
        {
            floatx4 zero = {0.f, 0.f, 0.f, 0.f};
            floatx4 acc[2][4];
            for (int rt = 0; rt < 2; rt++)
                for (int ct = 0; ct < 4; ct++) acc[rt][ct] = zero;
#pragma unroll
            for (int s = 0; s < 5; s++) {
                short8 a0 = load_x_frag(Xg, row0 + n16, s, q);
                short8 a1 = load_x_frag(Xg, row0 + 16 + n16, s, q);
#pragma unroll
                for (int ct = 0; ct < 4; ct++) {
                    int t = wave * 4 + ct;
                    short8 bf = *(const short8*)&w1p[((t * 5 + s) * 64 + lane) * 8];
                    acc[0][ct] = MFMA_BF16(a0, bf, acc[0][ct], 0, 0, 0);
                    acc[1][ct] = MFMA_BF16(a1, bf, acc[1][ct], 0, 0, 0);
                }
            }
#pragma unroll
            for (int ct = 0; ct < 4; ct++) {
                int col = (wave * 4 + ct) * 16 + n16;
                float bias = b1[col];
#pragma unroll
                for (int rt = 0; rt < 2; rt++)
#pragma unroll
                    for (int r = 0; r < 4; r++)
                        ldsH[(rt * 16 + q * 4 + r) * H1S + col] = f2bf(leaky(acc[rt][ct][r] + bias));
            }
        }
        __syncthreads();   // h1 published

        // L2 in 4x128-col chunks + L3 partial per chunk
        floatx4 acc3[2];
        {
            floatx4 zero = {0.f, 0.f, 0.f, 0.f};
            acc3[0] = zero; acc3[1] = zero;
        }
#pragma unroll
        for (int c = 0; c < 4; c++) {
            floatx4 zero = {0.f, 0.f, 0.f, 0.f};
            floatx4 acc[2][2];
            for (int rt = 0; rt < 2; rt++)
                for (int ct = 0; ct < 2; ct++) acc[rt][ct] = zero;
#pragma unroll
            for (int s = 0; s < 8; s++) {
                short8 a0 = *(const short8*)&ldsH[n16 * H1S + s * 32 + q * 8];
                short8 a1 = *(const short8*)&ldsH[(n16 + 16) * H1S + s * 32 + q * 8];
#pragma unroll
                for (int ct = 0; ct < 2; ct++) {
                    int tg = c * 8 + wave * 2 + ct;
                    short8 bf = *(const short8*)&w3p[((tg * 8 + s) * 64 + lane) * 8];
                    acc[0][ct] = MFMA_BF16(a0, bf, acc[0][ct], 0, 0, 0);
                    acc[1][ct] = MFMA_BF16(a1, bf, acc[1][ct], 0, 0, 0);
                }
            }
#pragma unroll
            for (int ct = 0; ct < 2; ct++) {
                int cl = (wave * 2 + ct) * 16 + n16;
                float bias = b3[c * 128 + cl];
#pragma unroll
                for (int rt = 0; rt < 2; rt++)
#pragma unroll
                    for (int r = 0; r < 4; r++)
                        ldsC[(rt * 16 + q * 4 + r) * CS + cl] = f2bf(leaky(acc[rt][ct][r] + bias));
            }
            __syncthreads();   // h2 chunk published
            // L3 partial: this chunk's 4 k-steps, one per wave
            {
                int sg = c * 4 + wave;   // global k-step 0..15
                short8 bf = *(const short8*)&wm2p[(sg * 64 + lane) * 8];
#pragma unroll
                for (int rt = 0; rt < 2; rt++) {
                    short8 a = *(const short8*)&ldsC[(rt * 16 + n16) * CS + wave * 32 + q * 8];
                    acc3[rt] = MFMA_BF16(a, bf, acc3[rt], 0, 0, 0);
                }
            }
            __syncthreads();   // chunk consumed
        }

        // reduce partial L3 sums across waves via pacc in ldsH (h1 dead)
        {
            float* pacc = (float*)ldsH;
#pragma unroll
            for (int rt = 0; rt < 2; rt++)
#pragma unroll
                for (int r = 0; r < 4; r++)
                    pacc[(wave * 32 + rt * 16 + q * 4 + r) * 16 + n16] = acc3[rt][r];
        }
        __syncthreads();
        {
            const float* pacc = (const float*)ldsH;
            for (int idx = tid; idx < 512; idx += 256) {
                int r = idx >> 4, c = idx & 15;
                float v = pacc[idx] + pacc[512 + idx] + pacc[1024 + idx] + pacc[1536 + idx];
                if (c < 14) sp_ws[(row0 + r) * 14 + c] = v + bm2[c];
            }
        }
    }
}

// ===========================================================================
// EnKF tail: one 64-thread wave per batch, no barriers (in-order LDS).
// ===========================================================================
__global__ __launch_bounds__(64) void enkf_tail(
    const float* __restrict__ sp_all,
    const float* __restrict__ on_w1, const float* __restrict__ on_b1,
    const float* __restrict__ on_w2, const float* __restrict__ on_b2,
    float* out)
{
    __shared__ float spv[32][14];
    __shared__ float ezv[32][14];
    __shared__ float smv[14], zzv[14], rrv[14];
    __shared__ float M[14][14], Kmat[14][14];
    __shared__ float G[14][28];
    __shared__ float fac[14];
    __shared__ float hbuf[32];

    const int l = threadIdx.x;
    const int b = blockIdx.x;

    for (int idx = l; idx < 448; idx += 64) ((float*)spv)[idx] = sp_all[b * 448 + idx];
    {
        const float* ezsrc = out + O4 + (b & 63) * 448;
        for (int idx = l; idx < 448; idx += 64) ((float*)ezv)[idx] = ezsrc[idx];
    }

    if (l < 14) {
        float s1 = 0.f, s2 = 0.f;
        for (int e = 0; e < 32; e++) { s1 += spv[e][l]; s2 += ezv[e][l]; }
        smv[l] = s1 * (1.f / 32.f);
        zzv[l] = s2 * (1.f / 32.f);
    }
    if (l < 32) {
        float t = on_b1[l];
        for (int k = 0; k < 14; k++) t += zzv[k] * on_w1[k * 32 + l];
        hbuf[l] = t > 0.f ? t : 0.f;
    }
    if (l < 14) {
        float t = on_b2[l];
        for (int k = 0; k < 32; k++) t += hbuf[k] * on_w2[k * 14 + l];
        t += 0.001f;
        rrv[l] = t * t + 0.038729833f;
    }
    for (int idx = l; idx < 196; idx += 64) {
        int i = idx / 14, j = idx - i * 14;
        float s = 0.f;
        for (int e = 0; e < 32; e++) s += (spv[e][i] - smv[i]) * (spv[e][j] - smv[j]);
        s *= (1.f / 31.f);
        M[i][j] = s;
        G[i][j] = s + (i == j ? rrv[i] : 0.f);
        G[i][14 + j] = (i == j) ? 1.f : 0.f;
    }
    // Gauss-Jordan (SPD, no pivoting), single-wave in-order
    for (int c = 0; c < 14; c++) {
        float pinv = 1.f / G[c][c];
        if (l < 28) G[c][l] *= pinv;
        if (l < 14 && l != c) fac[l] = G[l][c];
        for (int idx = l; idx < 392; idx += 64) {
            int i = idx / 28, j = idx - i * 28;
            if (i != c) G[i][j] -= fac[i] * G[c][j];
        }
    }
    for (int idx = l; idx < 196; idx += 64) {
        int i = idx / 14, j = idx - i * 14;
        float s = 0.f;
        for (int k = 0; k < 14; k++) s += M[i][k] * G[k][14 + j];
        Kmat[i][j] = s;
    }
    for (int idx = l; idx < 448; idx += 64) {
        int e = idx / 14, i = idx - e * 14;
        float g = 0.f;
        for (int j = 0; j < 14; j++) g += Kmat[i][j] * (ezv[e][j] - spv[e][j]);
        out[b * 448 + idx] = spv[e][i] + g;      // state_corrected
        out[O4 + b * 448 + idx] = ezv[e][i];     // ensemble_z
    }
    if (l < 14) {
        float g = 0.f;
        for (int j = 0; j < 14; j++) g += Kmat[l][j] * (zzv[j] - smv[j]);
        out[O1 + b * 14 + l] = smv[l] + g;       // corrected mean (linearity)
        out[O2 + b * 14 + l] = smv[l];           // state_m
        out[O3 + b * 14 + l] = zzv[l];           // z
    }
}

// ===========================================================================
extern "C" void kernel_launch(void* const* d_in, const int* in_sizes, int n_in,
                              void* d_out, int out_size, void* d_ws, size_t ws_size,
                              hipStream_t stream) {
    (void)in_sizes; (void)n_in; (void)out_size; (void)ws_size;
    // ws_size >= WS_BIG verified empirically in R6-R8 (merged path ran & passed).

    const float* raw_obs    = (const float*)d_in[0];
    const float* state_prev = (const float*)d_in[1];
    const float* pm_w1  = (const float*)d_in[2];
    const float* pm_b1  = (const float*)d_in[3];
    const float* pm_w3  = (const float*)d_in[4];
    const float* pm_b3  = (const float*)d_in[5];
    const float* pm_wm2 = (const float*)d_in[6];
    const float* pm_bm2 = (const float*)d_in[7];
    const float* sm_w2  = (const float*)d_in[8];
    const float* sm_b2  = (const float*)d_in[9];
    const float* sm_w3  = (const float*)d_in[10];
    const float* sm_b3  = (const float*)d_in[11];
    const float* sm_w5  = (const float*)d_in[12];
    const float* sm_b5  = (const float*)d_in[13];
    const float* sm_w6  = (const float*)d_in[14];
    const float* sm_b6  = (const float*)d_in[15];
    const float* on_w1  = (const float*)d_in[16];
    const float* on_b1  = (const float*)d_in[17];
    const float* on_w2  = (const float*)d_in[18];
    const float* on_b2  = (const float*)d_in[19];

    float* out = (float*)d_out;
    u16* P = (u16*)d_ws;
    float* sp_ws = (float*)((char*)d_ws + WS_NEEDED);

    PackArgs pa;
    pa.seg[0] = { pm_w1,  140, 256, 5,  PW1,  40960  };
    pa.seg[1] = { pm_w3,  256, 512, 8,  PW3,  131072 };
    pa.seg[2] = { pm_wm2, 512, 14,  16, PWM2, 8192   };
    pa.seg[3] = { sm_w2,  220, 256, 7,  PSW2, 57344  };
    pa.seg[4] = { sm_w3,  256, 256, 8,  PSW3, 65536  };
    pa.seg[5] = { sm_w5,  256, 64,  8,  PSW5, 16384  };
    pa.seg[6] = { sm_w6,  64,  14,  2,  PSW6, 1024   };
    pack_all<<<(PTOTAL + 255) / 256, 256, 0, stream>>>(pa, P);

    merged_mlp<<<2112, 256, 0, stream>>>(raw_obs, state_prev, P,
                                         pm_b1, pm_b3, pm_bm2,
                                         sm_b2, sm_b3, sm_b5, sm_b6,
                                         out + O4, sp_ws);
    enkf_tail<<<2048, 64, 0, stream>>>(sp_ws, on_w1, on_b1, on_w2, on_b2, out);
}